// Round 4
// baseline (411.391 us; speedup 1.0000x reference)
//
#include <hip/hip_runtime.h>
#include <stdint.h>

typedef unsigned short u16;
typedef __attribute__((ext_vector_type(8))) short short8;
typedef __attribute__((ext_vector_type(4))) short short4b;
typedef __attribute__((ext_vector_type(4))) float f32x4;

#define MFMA16 __builtin_amdgcn_mfma_f32_16x16x32_bf16

__device__ __forceinline__ u16 f2b(float f) {
  union { float f; uint32_t i; } x; x.f = f;
  uint32_t r = x.i + 0x7FFFu + ((x.i >> 16) & 1u);
  return (u16)(r >> 16);
}
__device__ __forceinline__ float b2f(u16 u) {
  union { uint32_t i; float f; } x; x.i = ((uint32_t)u) << 16; return x.f;
}

// async global->LDS, 16B per lane. HW semantics: LDS dest = wave-uniform
// base (lane0's value) + lane*16; global src is per-lane.
__device__ __forceinline__ void gload16(const u16* g, u16* l) {
  __builtin_amdgcn_global_load_lds(
      (const __attribute__((address_space(1))) void*)g,
      (__attribute__((address_space(3))) void*)l, 16, 0, 0);
}

// ---------------------------------------------------------------------------
// fp32 -> bf16 convert (n divisible by 4)
// ---------------------------------------------------------------------------
__global__ __launch_bounds__(256) void cvt_k(const float* __restrict__ src,
                                             u16* __restrict__ dst, int n) {
  const int i = (blockIdx.x * 256 + threadIdx.x) * 4;
  if (i < n) {
    const float4 v = *(const float4*)(src + i);
    dst[i + 0] = f2b(v.x); dst[i + 1] = f2b(v.y);
    dst[i + 2] = f2b(v.z); dst[i + 3] = f2b(v.w);
  }
}

// ---------------------------------------------------------------------------
// Weight transpose + convert: src fp32 [1280][1280] -> dst bf16 transposed
// ---------------------------------------------------------------------------
struct TransArgs { const float* src[2]; u16* dst[2]; };

__global__ __launch_bounds__(512) void transpose_k(TransArgs a) {
  const int m = blockIdx.z;
  const int r0 = blockIdx.y * 64;
  const int c0 = blockIdx.x * 64;
  const float* src = a.src[m];
  u16* dst = a.dst[m];
  __shared__ u16 t[64][65];
  const int tx = threadIdx.x, ty = threadIdx.y;   // 64 x 8
#pragma unroll
  for (int i = 0; i < 64; i += 8)
    t[ty + i][tx] = f2b(src[(size_t)(r0 + ty + i) * 1280 + c0 + tx]);
  __syncthreads();
#pragma unroll
  for (int i = 0; i < 64; i += 8)
    dst[(size_t)(c0 + ty + i) * 1280 + r0 + tx] = t[tx][ty + i];
}

// ---------------------------------------------------------------------------
// GEMM: C[M][N] = A[M][K] @ B[K][N], A/BT bf16, fp32 acc. BT[N][K].
// m97 structure — 128x128 tile, BK=64, 4 waves (each 64x64),
// global_load_lds width=16 staging, single-buffered, 2 barriers/K-tile.
// LDS layout: row-major [128][64] u16 with k-octet XOR swizzle:
//   element (row, k) at row*64 + ((k>>3) ^ (row&7))*8 + (k&7).
// Staging source pre-applies the same XOR (involution), so each row's 128B
// stays contiguous in global (fully coalesced) and LDS writes are linear.
// F32OUT: writes fp32 with fused +bias[N]+resid[M][N]; else bf16.
// ---------------------------------------------------------------------------
template <bool F32OUT>
__global__ __launch_bounds__(256) void gemm_bt(
    const u16* __restrict__ A, const u16* __restrict__ BT,
    u16* __restrict__ C16, float* __restrict__ C32,
    int M, int N, int K,
    const float* __restrict__ bias, const float* __restrict__ resid) {
  __shared__ __align__(16) u16 As[8192];   // 128 rows x 64 k
  __shared__ __align__(16) u16 Bs[8192];
  const int tid = threadIdx.x;
  const int w = tid >> 6, lane = tid & 63;
  const int l15 = lane & 15, quad = lane >> 4;
  const int m0 = blockIdx.x * 128, n0 = blockIdx.y * 128;
  const int wm = w >> 1, wn = w & 1;

  // staging addressing: call s (s=0..3) covers u16 [s*2048, s*2048+2048).
  // thread tid -> row = s*32 + (tid>>3), lds chunk = tid&7,
  // global chunk = (tid&7) ^ (row&7)  (s*32 = 0 mod 8).
  const int rowa = tid >> 3;
  const int cgx = (tid & 7) ^ (rowa & 7);
  const u16* pa = A  + (size_t)(m0 + rowa) * K + cgx * 8;
  const u16* pb = BT + (size_t)(n0 + rowa) * K + cgx * 8;
  u16* la = As + tid * 8;
  u16* lb = Bs + tid * 8;

  f32x4 acc[4][4];
#pragma unroll
  for (int i = 0; i < 4; i++)
#pragma unroll
    for (int j = 0; j < 4; j++) acc[i][j] = (f32x4){0.f, 0.f, 0.f, 0.f};

  for (int kt = 0; kt < K; kt += 64) {
#pragma unroll
    for (int s = 0; s < 4; s++) {
      const size_t go = (size_t)(s * 32) * K + kt;
      gload16(pa + go, la + s * 2048);
      gload16(pb + go, lb + s * 2048);
    }
    __syncthreads();   // compiler drains vmcnt(0) before s_barrier

#pragma unroll
    for (int ks = 0; ks < 2; ks++) {
      short8 af[4], bfr[4];
#pragma unroll
      for (int i = 0; i < 4; i++) {
        const int arow = wm * 64 + i * 16 + l15;
        const int brow = wn * 64 + i * 16 + l15;
        const int ch = ((ks * 4 + quad) ^ (l15 & 7)) * 8;
        af[i]  = *(const short8*)(As + arow * 64 + ch);
        bfr[i] = *(const short8*)(Bs + brow * 64 + ch);
      }
#pragma unroll
      for (int i = 0; i < 4; i++)
#pragma unroll
        for (int j = 0; j < 4; j++)
          acc[i][j] = MFMA16(af[i], bfr[j], acc[i][j], 0, 0, 0);
    }
    __syncthreads();   // frag reads done before next tile overwrites
  }

#pragma unroll
  for (int i = 0; i < 4; i++) {
    const int row0 = m0 + wm * 64 + i * 16 + quad * 4;
#pragma unroll
    for (int j = 0; j < 4; j++) {
      const int col = n0 + wn * 64 + j * 16 + l15;
      const float bv2 = F32OUT ? bias[col] : 0.f;
#pragma unroll
      for (int r = 0; r < 4; r++) {
        const size_t idx = (size_t)(row0 + r) * N + col;
        if (F32OUT) {
          C32[idx] = acc[i][j][r] + bv2 + resid[idx];
        } else {
          C16[idx] = f2b(acc[i][j][r]);
        }
      }
    }
  }
}

// ---------------------------------------------------------------------------
// KV projection: 8 fp32 weight mats [2048][1280] applied to the segment's
// fp32 encoder tokens. R4: 4-wave blocks, wave w owns output cols
// [n0+w*16, n0+w*16+16) with the FULL K=2048 loop (no cross-wave state;
// verbatim R2 per-wave logic with jj := w). 2560 waves total (~10/CU) vs
// R2's 640 — the in-flight-latency fix without R3's buggy LDS reduce.
// K out -> Kws[b][key][1280]; V out -> VTws[b][h][d][128].
// ---------------------------------------------------------------------------
struct KVArgs {
  const float* ehs;      // fp32 [2][101][2048]
  const float* w[8];     // fp32 [2048][1280]: k_txt,v_txt,k_obj,v_obj,k_oth,v_oth,k_ip,v_ip
  u16* Kws;              // bf16 [2][101][1280]
  u16* VTws;             // bf16 [2][20][64][128]
};

__global__ __launch_bounds__(256) void kv_proj(KVArgs a) {
  const int bx = blockIdx.x;          // 0..31
  const int b = bx >> 4;
  const int r = bx & 15;
  int mat, mt;
  if (r < 5)       { mat = 0; mt = r; }
  else if (r < 10) { mat = 1; mt = r - 5; }
  else             { mat = 2 + (r - 10); mt = 0; }
  const int seg = mat >> 1;
  const int soff4[4] = {0, 77, 81, 85};
  const int slen4[4] = {77, 4, 4, 16};
  const int soff = soff4[seg], slen = slen4[seg];
  const int n0 = blockIdx.y * 64;
  const int tid = threadIdx.x;
  const int w = tid >> 6;             // wave id: 16-col chunk
  const int lane = tid & 63, l15 = lane & 15, quad = lane >> 4;
  int tl = mt * 16 + l15; if (tl >= slen) tl = slen - 1;   // clamp; masked at store
  const float* Arow = a.ehs + ((size_t)b * 101 + soff + tl) * 2048;
  const float* W = a.w[mat];
  f32x4 acc = (f32x4){0.f, 0.f, 0.f, 0.f};
  for (int k = 0; k < 2048; k += 32) {
    const float4 a0 = *(const float4*)(Arow + k + quad * 8);
    const float4 a1 = *(const float4*)(Arow + k + quad * 8 + 4);
    short8 af;
    af[0] = (short)f2b(a0.x); af[1] = (short)f2b(a0.y);
    af[2] = (short)f2b(a0.z); af[3] = (short)f2b(a0.w);
    af[4] = (short)f2b(a1.x); af[5] = (short)f2b(a1.y);
    af[6] = (short)f2b(a1.z); af[7] = (short)f2b(a1.w);
    const float* wcol = W + (size_t)(k + quad * 8) * 1280 + n0 + w * 16 + l15;
    short8 bf_;
#pragma unroll
    for (int j = 0; j < 8; j++) bf_[j] = (short)f2b(wcol[(size_t)j * 1280]);
    acc = MFMA16(af, bf_, acc, 0, 0, 0);
  }
  const bool isK = !(mat & 1);
#pragma unroll
  for (int rr = 0; rr < 4; rr++) {
    const int tloc = mt * 16 + quad * 4 + rr;
    if (tloc >= slen) continue;
    const int key = soff + tloc;
    const int col = n0 + w * 16 + l15;
    const u16 v = f2b(acc[rr]);
    if (isK) {
      a.Kws[((size_t)b * 101 + key) * 1280 + col] = v;
    } else {
      const int hh = col >> 6, dd = col & 63;
      a.VTws[((size_t)(b * 20 + hh) * 64 + dd) * 128 + key] = v;
    }
  }
}

// ---------------------------------------------------------------------------
// Fused segmented attention. Block = (b, h, 64 queries), 4 waves.
// Keys padded: 112 for QK (7 tiles), 128 for PV (4 k-steps), zero-filled.
// LDS frag layout: elem (i,k) of an [I][Kd] tile at
// ((i/16)*(Kd/32) + k/32)*512 + ((k%32)/8)*128 + (i%16)*8 + (k%8).
//
// Swapped QK^T (mfma(K,Q)) so each lane holds its query's 28 scores
// (keys t*16+quad*4+r, query=l15) in REGISTERS; segmented softmax is
// per-lane predicated passes + 2x shfl_xor(16,32) over the quad group.
// ---------------------------------------------------------------------------
__global__ __launch_bounds__(256) void attn_k(
    const u16* __restrict__ Q, const u16* __restrict__ Kws,
    const u16* __restrict__ VT, u16* __restrict__ O) {
  const int s0 = blockIdx.x * 64;
  const int h  = blockIdx.y;
  const int b  = blockIdx.z;
  const int tid = threadIdx.x;
  const int w = tid >> 6, lane = tid & 63, l15 = lane & 15, quad = lane >> 4;

  __shared__ __align__(16) u16 KP[8192];  // K tiles (7168 used), then reused as P
  __shared__ __align__(16) u16 Vt[8192];  // V^T

  // stage K: [key<112][d<64]
  for (int e = tid; e < 7168; e += 256) {
    const int key = e >> 6, d = e & 63;
    u16 v = 0;
    if (key < 101) v = Kws[((size_t)b * 101 + key) * 1280 + h * 64 + d];
    const int off = ((key >> 4) * 2 + (d >> 5)) * 512 + ((d >> 3) & 3) * 128 + (key & 15) * 8 + (d & 7);
    KP[off] = v;
  }
  // stage V^T: [d<64][key<128]
  for (int e = tid; e < 8192; e += 256) {
    const int d = e >> 7, key = e & 127;
    u16 v = 0;
    if (key < 101) v = VT[((size_t)(b * 20 + h) * 64 + d) * 128 + key];
    const int off = ((d >> 4) * 4 + (key >> 5)) * 512 + ((key >> 3) & 3) * 128 + (d & 15) * 8 + (key & 7);
    Vt[off] = v;
  }
  // Q fragments straight from global (B-operand: n=l15 -> query, k=quad*8+j)
  const u16* qrow = Q + ((size_t)b * 4096 + s0 + w * 16 + l15) * 1280 + h * 64;
  const short8 qf0 = *(const short8*)(qrow + quad * 8);
  const short8 qf1 = *(const short8*)(qrow + 32 + quad * 8);
  __syncthreads();

  // S^T = K Q^T (7 key-tiles x 2 k-steps). D: col=l15=query, row=quad*4+r=key.
  f32x4 sc[7];
#pragma unroll
  for (int t = 0; t < 7; t++) {
    f32x4 a = (f32x4){0.f, 0.f, 0.f, 0.f};
    const short8 k0 = *(const short8*)(KP + (t * 2 + 0) * 512 + quad * 128 + l15 * 8);
    const short8 k1 = *(const short8*)(KP + (t * 2 + 1) * 512 + quad * 128 + l15 * 8);
    a = MFMA16(k0, qf0, a, 0, 0, 0);
    a = MFMA16(k1, qf1, a, 0, 0, 0);
    sc[t] = a;
  }

  // ---- segmented softmax, fully in registers ----
  float sv[7][4];
#pragma unroll
  for (int t = 0; t < 7; t++)
#pragma unroll
    for (int r = 0; r < 4; r++) sv[t][r] = sc[t][r] * 0.125f;

  const int kb = quad * 4;
  float mx0 = -1e30f, mx1 = -1e30f, mx2 = -1e30f, mx3 = -1e30f;
#pragma unroll
  for (int t = 0; t < 7; t++)
#pragma unroll
    for (int r = 0; r < 4; r++) {
      const int key = t * 16 + kb + r;
      const float v = sv[t][r];
      if (key < 77)       mx0 = fmaxf(mx0, v);
      else if (key < 81)  mx1 = fmaxf(mx1, v);
      else if (key < 85)  mx2 = fmaxf(mx2, v);
      else if (key < 101) mx3 = fmaxf(mx3, v);
    }
  mx0 = fmaxf(mx0, __shfl_xor(mx0, 16, 64)); mx0 = fmaxf(mx0, __shfl_xor(mx0, 32, 64));
  mx1 = fmaxf(mx1, __shfl_xor(mx1, 16, 64)); mx1 = fmaxf(mx1, __shfl_xor(mx1, 32, 64));
  mx2 = fmaxf(mx2, __shfl_xor(mx2, 16, 64)); mx2 = fmaxf(mx2, __shfl_xor(mx2, 32, 64));
  mx3 = fmaxf(mx3, __shfl_xor(mx3, 16, 64)); mx3 = fmaxf(mx3, __shfl_xor(mx3, 32, 64));

  float sm0 = 0.f, sm1 = 0.f, sm2 = 0.f, sm3 = 0.f;
#pragma unroll
  for (int t = 0; t < 7; t++)
#pragma unroll
    for (int r = 0; r < 4; r++) {
      const int key = t * 16 + kb + r;
      float e = 0.f;
      if (key < 77)       { e = __expf(sv[t][r] - mx0); sm0 += e; }
      else if (key < 81)  { e = __expf(sv[t][r] - mx1); sm1 += e; }
      else if (key < 85)  { e = __expf(sv[t][r] - mx2); sm2 += e; }
      else if (key < 101) { e = __expf(sv[t][r] - mx3); sm3 += e; }
      sv[t][r] = e;   // pads (key>=101) stay 0
    }
  sm0 += __shfl_xor(sm0, 16, 64); sm0 += __shfl_xor(sm0, 32, 64);
  sm1 += __shfl_xor(sm1, 16, 64); sm1 += __shfl_xor(sm1, 32, 64);
  sm2 += __shfl_xor(sm2, 16, 64); sm2 += __shfl_xor(sm2, 32, 64);
  sm3 += __shfl_xor(sm3, 16, 64); sm3 += __shfl_xor(sm3, 32, 64);
  const float inv0 = 1.f / sm0, inv1 = 1.f / sm1, inv2 = 1.f / sm2, inv3 = 1.f / sm3;
#pragma unroll
  for (int t = 0; t < 7; t++)
#pragma unroll
    for (int r = 0; r < 4; r++) {
      const int key = t * 16 + kb + r;
      const float f = key < 77 ? inv0 : key < 81 ? inv1 : key < 85 ? inv2 : inv3;
      sv[t][r] *= f;
    }

  // all waves' K-tile reads must finish before P overwrites KP
  __syncthreads();

  // write P (bf16) into KP in the PV A-operand frag layout for wave w
#pragma unroll
  for (int t = 0; t < 7; t++) {
    const int key0 = t * 16 + kb;
    const int off = (w * 4 + (key0 >> 5)) * 512 + ((key0 >> 3) & 3) * 128 + l15 * 8 + (key0 & 7);
    short4b pv;
    pv[0] = (short)f2b(sv[t][0]); pv[1] = (short)f2b(sv[t][1]);
    pv[2] = (short)f2b(sv[t][2]); pv[3] = (short)f2b(sv[t][3]);
    *(short4b*)(KP + off) = pv;
  }
  // zero pad keys 112..127 (ks=3 upper chunks)
  if (quad < 2)
    *(short8*)(KP + (w * 4 + 3) * 512 + (quad + 2) * 128 + l15 * 8) =
        (short8){0, 0, 0, 0, 0, 0, 0, 0};

  // O = P V  (4 k-steps x 4 d-tiles); same-wave P write->read ordered by lgkmcnt
  f32x4 oacc[4];
#pragma unroll
  for (int dsm = 0; dsm < 4; dsm++) oacc[dsm] = (f32x4){0.f, 0.f, 0.f, 0.f};
#pragma unroll
  for (int ks = 0; ks < 4; ks++) {
    const short8 pf = *(const short8*)(KP + (w * 4 + ks) * 512 + quad * 128 + l15 * 8);
#pragma unroll
    for (int dsm = 0; dsm < 4; dsm++) {
      const short8 vf = *(const short8*)(Vt + (dsm * 4 + ks) * 512 + quad * 128 + l15 * 8);
      oacc[dsm] = MFMA16(pf, vf, oacc[dsm], 0, 0, 0);
    }
  }
  u16* orow = O + ((size_t)b * 4096 + s0 + w * 16) * 1280 + h * 64;
#pragma unroll
  for (int dsm = 0; dsm < 4; dsm++)
#pragma unroll
    for (int r = 0; r < 4; r++)
      orow[(size_t)(quad * 4 + r) * 1280 + dsm * 16 + l15] = f2b(oacc[dsm][r]);
}

// ---------------------------------------------------------------------------
extern "C" void kernel_launch(void* const* d_in, const int* in_sizes, int n_in,
                              void* d_out, int out_size, void* d_ws, size_t ws_size,
                              hipStream_t stream) {
  const float* HS  = (const float*)d_in[0];   // [2][4096][1280] fp32
  const float* EHS = (const float*)d_in[1];   // [2][101][2048]  fp32
  const float* Wq  = (const float*)d_in[2];
  const float* Wo  = (const float*)d_in[11];
  const float* Bo  = (const float*)d_in[12];

  // workspace: ~28.7 MB. HSb aliases AO (HSb dead after Q-GEMM);
  // Qb (bf16 scratch) lives inside the fp32 d_out (dead before final write).
  u16* ws = (u16*)d_ws;
  u16* HSb  = ws;                      ws += (size_t)8192 * 1280;
  u16* AO   = HSb;
  u16* WqT  = ws;                      ws += (size_t)1280 * 1280;
  u16* WoT  = ws;                      ws += (size_t)1280 * 1280;
  u16* Kws  = ws;                      ws += (size_t)2 * 101 * 1280;
  u16* VTw  = ws;                      ws += (size_t)2 * 20 * 64 * 128;
  u16* Qb   = (u16*)d_out;
  (void)ws_size; (void)in_sizes; (void)n_in; (void)out_size;

  // fp32 -> bf16 hidden states
  cvt_k<<<dim3(8192 * 1280 / 4 / 256), 256, 0, stream>>>(HS, HSb, 8192 * 1280);

  // Wq / Wo transpose (+convert)
  TransArgs ta;
  ta.src[0] = Wq; ta.dst[0] = WqT;
  ta.src[1] = Wo; ta.dst[1] = WoT;
  transpose_k<<<dim3(20, 20, 2), dim3(64, 8), 0, stream>>>(ta);

  // Q projection (bf16 out, into d_out scratch)
  gemm_bt<false><<<dim3(64, 10), 256, 0, stream>>>(HSb, WqT, Qb, nullptr,
                                                   8192, 1280, 1280, nullptr, nullptr);

  // KV projections (fp32 inputs read directly); 4-wave col-split blocks
  KVArgs ka;
  ka.ehs = EHS;
  for (int i = 0; i < 8; i++) ka.w[i] = (const float*)d_in[3 + i];
  ka.Kws = Kws; ka.VTws = VTw;
  kv_proj<<<dim3(32, 20), 256, 0, stream>>>(ka);

  // fused segmented attention (AO overwrites dead HSb)
  attn_k<<<dim3(64, 20, 2), 256, 0, stream>>>(Qb, Kws, VTw, AO);

  // out projection + bias + residual -> fp32 d_out (overwrites dead Qb)
  gemm_bt<true><<<dim3(64, 10), 256, 0, stream>>>(AO, WoT, nullptr, (float*)d_out,
                                                  8192, 1280, 1280, Bo, HS);
}

// Round 5
// 369.406 us; speedup vs baseline: 1.1137x; 1.1137x over previous
//
#include <hip/hip_runtime.h>
#include <stdint.h>

typedef unsigned short u16;
typedef __attribute__((ext_vector_type(8))) short short8;
typedef __attribute__((ext_vector_type(4))) short short4b;
typedef __attribute__((ext_vector_type(4))) float f32x4;

#define MFMA16 __builtin_amdgcn_mfma_f32_16x16x32_bf16

__device__ __forceinline__ u16 f2b(float f) {
  union { float f; uint32_t i; } x; x.f = f;
  uint32_t r = x.i + 0x7FFFu + ((x.i >> 16) & 1u);
  return (u16)(r >> 16);
}
__device__ __forceinline__ float b2f(u16 u) {
  union { uint32_t i; float f; } x; x.i = ((uint32_t)u) << 16; return x.f;
}

// async global->LDS, 16B per lane. HW semantics: LDS dest = wave-uniform
// base (lane0's value) + lane*16; global src is per-lane.
__device__ __forceinline__ void gload16(const u16* g, u16* l) {
  __builtin_amdgcn_global_load_lds(
      (const __attribute__((address_space(1))) void*)g,
      (__attribute__((address_space(3))) void*)l, 16, 0, 0);
}

// ---------------------------------------------------------------------------
// fp32 -> bf16 convert (n divisible by 4)
// ---------------------------------------------------------------------------
__global__ __launch_bounds__(256) void cvt_k(const float* __restrict__ src,
                                             u16* __restrict__ dst, int n) {
  const int i = (blockIdx.x * 256 + threadIdx.x) * 4;
  if (i < n) {
    const float4 v = *(const float4*)(src + i);
    dst[i + 0] = f2b(v.x); dst[i + 1] = f2b(v.y);
    dst[i + 2] = f2b(v.z); dst[i + 3] = f2b(v.w);
  }
}

// ---------------------------------------------------------------------------
// Weight transpose + convert: src fp32 [1280][1280] -> dst bf16 transposed
// ---------------------------------------------------------------------------
struct TransArgs { const float* src[2]; u16* dst[2]; };

__global__ __launch_bounds__(512) void transpose_k(TransArgs a) {
  const int m = blockIdx.z;
  const int r0 = blockIdx.y * 64;
  const int c0 = blockIdx.x * 64;
  const float* src = a.src[m];
  u16* dst = a.dst[m];
  __shared__ u16 t[64][65];
  const int tx = threadIdx.x, ty = threadIdx.y;   // 64 x 8
#pragma unroll
  for (int i = 0; i < 64; i += 8)
    t[ty + i][tx] = f2b(src[(size_t)(r0 + ty + i) * 1280 + c0 + tx]);
  __syncthreads();
#pragma unroll
  for (int i = 0; i < 64; i += 8)
    dst[(size_t)(c0 + ty + i) * 1280 + r0 + tx] = t[tx][ty + i];
}

// ---------------------------------------------------------------------------
// GEMM: C[M][N] = A[M][K] @ B[K][N], A/BT bf16, fp32 acc. BT[N][K].
// m97 structure — 128x128 tile, BK=64, 4 waves (each 64x64),
// global_load_lds width=16 staging, single-buffered, 2 barriers/K-tile.
// LDS layout: row-major [128][64] u16 with k-octet XOR swizzle:
//   element (row, k) at row*64 + ((k>>3) ^ (row&7))*8 + (k&7).
// Staging source pre-applies the same XOR (involution), so each row's 128B
// stays contiguous in global (fully coalesced) and LDS writes are linear.
// F32OUT: writes fp32 with fused +bias[N]+resid[M][N]; else bf16.
// ---------------------------------------------------------------------------
template <bool F32OUT>
__global__ __launch_bounds__(256) void gemm_bt(
    const u16* __restrict__ A, const u16* __restrict__ BT,
    u16* __restrict__ C16, float* __restrict__ C32,
    int M, int N, int K,
    const float* __restrict__ bias, const float* __restrict__ resid) {
  __shared__ __align__(16) u16 As[8192];   // 128 rows x 64 k
  __shared__ __align__(16) u16 Bs[8192];
  const int tid = threadIdx.x;
  const int w = tid >> 6, lane = tid & 63;
  const int l15 = lane & 15, quad = lane >> 4;
  const int m0 = blockIdx.x * 128, n0 = blockIdx.y * 128;
  const int wm = w >> 1, wn = w & 1;

  // staging addressing: call s (s=0..3) covers u16 [s*2048, s*2048+2048).
  // thread tid -> row = s*32 + (tid>>3), lds chunk = tid&7,
  // global chunk = (tid&7) ^ (row&7)  (s*32 = 0 mod 8).
  const int rowa = tid >> 3;
  const int cgx = (tid & 7) ^ (rowa & 7);
  const u16* pa = A  + (size_t)(m0 + rowa) * K + cgx * 8;
  const u16* pb = BT + (size_t)(n0 + rowa) * K + cgx * 8;
  u16* la = As + tid * 8;
  u16* lb = Bs + tid * 8;

  f32x4 acc[4][4];
#pragma unroll
  for (int i = 0; i < 4; i++)
#pragma unroll
    for (int j = 0; j < 4; j++) acc[i][j] = (f32x4){0.f, 0.f, 0.f, 0.f};

  for (int kt = 0; kt < K; kt += 64) {
#pragma unroll
    for (int s = 0; s < 4; s++) {
      const size_t go = (size_t)(s * 32) * K + kt;
      gload16(pa + go, la + s * 2048);
      gload16(pb + go, lb + s * 2048);
    }
    __syncthreads();   // compiler drains vmcnt(0) before s_barrier

#pragma unroll
    for (int ks = 0; ks < 2; ks++) {
      short8 af[4], bfr[4];
#pragma unroll
      for (int i = 0; i < 4; i++) {
        const int arow = wm * 64 + i * 16 + l15;
        const int brow = wn * 64 + i * 16 + l15;
        const int ch = ((ks * 4 + quad) ^ (l15 & 7)) * 8;
        af[i]  = *(const short8*)(As + arow * 64 + ch);
        bfr[i] = *(const short8*)(Bs + brow * 64 + ch);
      }
#pragma unroll
      for (int i = 0; i < 4; i++)
#pragma unroll
        for (int j = 0; j < 4; j++)
          acc[i][j] = MFMA16(af[i], bfr[j], acc[i][j], 0, 0, 0);
    }
    __syncthreads();   // frag reads done before next tile overwrites
  }

#pragma unroll
  for (int i = 0; i < 4; i++) {
    const int row0 = m0 + wm * 64 + i * 16 + quad * 4;
#pragma unroll
    for (int j = 0; j < 4; j++) {
      const int col = n0 + wn * 64 + j * 16 + l15;
      const float bv2 = F32OUT ? bias[col] : 0.f;
#pragma unroll
      for (int r = 0; r < 4; r++) {
        const size_t idx = (size_t)(row0 + r) * N + col;
        if (F32OUT) {
          C32[idx] = acc[i][j][r] + bv2 + resid[idx];
        } else {
          C16[idx] = f2b(acc[i][j][r]);
        }
      }
    }
  }
}

// ---------------------------------------------------------------------------
// KV projection. R5: LDS-staged wide loads. Per BK=64 tile, the 256-thread
// block loads W[64k][64c] fp32 row-major (float4, contiguous 256B segments),
// converts to bf16 and scatter-writes a column-major swizzled LDS tile
// ("BT" layout); MFMA fragments then read conflict-free ds_read_b128 using
// the proven gemm_bt octet-XOR. Col-spread term (col+(col>>3))&7 makes the
// transpose ds_writes span all 8 octets per instruction (~4-way worst).
// A (tokens) staged the same way. T14 split: next-tile global loads issued
// before compute, LDS writes after the barrier. Wave w owns cols
// [n0+w*16, +16); store epilogue verbatim from the passing R4 kernel.
// Replaces the scattered per-column dword loads (R2/R4 both sat at ~15cy
// per scattered wave64 VMEM instr = the real limiter).
// ---------------------------------------------------------------------------
struct KVArgs {
  const float* ehs;      // fp32 [2][101][2048]
  const float* w[8];     // fp32 [2048][1280]: k_txt,v_txt,k_obj,v_obj,k_oth,v_oth,k_ip,v_ip
  u16* Kws;              // bf16 [2][101][1280]
  u16* VTws;             // bf16 [2][20][64][128]
};

__global__ __launch_bounds__(256) void kv_proj(KVArgs a) {
  const int bx = blockIdx.x;          // 0..31
  const int b = bx >> 4;
  const int r = bx & 15;
  int mat, mt;
  if (r < 5)       { mat = 0; mt = r; }
  else if (r < 10) { mat = 1; mt = r - 5; }
  else             { mat = 2 + (r - 10); mt = 0; }
  const int seg = mat >> 1;
  const int soff4[4] = {0, 77, 81, 85};
  const int slen4[4] = {77, 4, 4, 16};
  const int soff = soff4[seg], slen = slen4[seg];
  const int n0 = blockIdx.y * 64;
  const int tid = threadIdx.x;
  const int w = tid >> 6;             // wave id: 16-col chunk
  const int lane = tid & 63, l15 = lane & 15, quad = lane >> 4;
  const float* W = a.w[mat];

  __shared__ __align__(16) u16 Wt[4096];  // [64 col][64 k] swizzled bf16
  __shared__ __align__(16) u16 At[1024];  // [16 tok][64 k] swizzled bf16

  // A staging map: thread -> (token row, k-float4)
  const int ar = tid >> 4, af4 = tid & 15;
  int tok = mt * 16 + ar; if (tok >= slen) tok = slen - 1;   // clamp (masked at store)
  const float* Arow = a.ehs + ((size_t)b * 101 + soff + tok) * 2048;

  float4 wreg[4]; float4 areg;
  // preload tile 0
#pragma unroll
  for (int rep = 0; rep < 4; rep++) {
    const int idx = rep * 256 + tid;
    const int kr = idx >> 4, f4 = idx & 15;
    wreg[rep] = *(const float4*)(W + (size_t)kr * 1280 + n0 + f4 * 4);
  }
  areg = *(const float4*)(Arow + af4 * 4);

  f32x4 acc = (f32x4){0.f, 0.f, 0.f, 0.f};
  const int colw = w * 16 + l15;                 // wave's col within the 64-chunk
  const int colp = (colw + (colw >> 3)) & 7;     // col-spread swizzle class

  for (int t = 0; t < 32; ++t) {
    // write staged regs -> LDS (transpose W on the fly)
#pragma unroll
    for (int rep = 0; rep < 4; rep++) {
      const int idx = rep * 256 + tid;
      const int kr = idx >> 4, f4 = idx & 15;
      const float wsv[4] = {wreg[rep].x, wreg[rep].y, wreg[rep].z, wreg[rep].w};
#pragma unroll
      for (int i = 0; i < 4; i++) {
        const int col = f4 * 4 + i;
        const int oct = (kr >> 3) ^ ((col + (col >> 3)) & 7);
        Wt[col * 64 + oct * 8 + (kr & 7)] = f2b(wsv[i]);
      }
    }
    {
      short4b av4;
      av4[0] = (short)f2b(areg.x); av4[1] = (short)f2b(areg.y);
      av4[2] = (short)f2b(areg.z); av4[3] = (short)f2b(areg.w);
      *(short4b*)(At + ar * 64 + (((af4 >> 1) ^ (ar & 7)) * 8) + (af4 & 1) * 4) = av4;
    }
    __syncthreads();

    // issue next-tile global loads (land during compute; consumed next iter)
    if (t + 1 < 32) {
      const int k0 = (t + 1) * 64;
#pragma unroll
      for (int rep = 0; rep < 4; rep++) {
        const int idx = rep * 256 + tid;
        const int kr = idx >> 4, f4 = idx & 15;
        wreg[rep] = *(const float4*)(W + (size_t)(k0 + kr) * 1280 + n0 + f4 * 4);
      }
      areg = *(const float4*)(Arow + k0 + af4 * 4);
    }

    // compute from LDS: 2 k-steps of 32
#pragma unroll
    for (int ks = 0; ks < 2; ks++) {
      const short8 af = *(const short8*)(At + l15 * 64 + (((ks * 4 + quad) ^ (l15 & 7)) * 8));
      const short8 bf = *(const short8*)(Wt + colw * 64 + (((ks * 4 + quad) ^ colp) * 8));
      acc = MFMA16(af, bf, acc, 0, 0, 0);
    }
    __syncthreads();   // reads done before next tile's LDS writes
  }

  const bool isK = !(mat & 1);
#pragma unroll
  for (int rr = 0; rr < 4; rr++) {
    const int tloc = mt * 16 + quad * 4 + rr;
    if (tloc >= slen) continue;
    const int key = soff + tloc;
    const int col = n0 + w * 16 + l15;
    const u16 v = f2b(acc[rr]);
    if (isK) {
      a.Kws[((size_t)b * 101 + key) * 1280 + col] = v;
    } else {
      const int hh = col >> 6, dd = col & 63;
      a.VTws[((size_t)(b * 20 + hh) * 64 + dd) * 128 + key] = v;
    }
  }
}

// ---------------------------------------------------------------------------
// Fused segmented attention. Block = (b, h, 64 queries), 4 waves.
// Keys padded: 112 for QK (7 tiles), 128 for PV (4 k-steps), zero-filled.
// LDS frag layout: elem (i,k) of an [I][Kd] tile at
// ((i/16)*(Kd/32) + k/32)*512 + ((k%32)/8)*128 + (i%16)*8 + (k%8).
//
// Swapped QK^T (mfma(K,Q)) so each lane holds its query's 28 scores
// (keys t*16+quad*4+r, query=l15) in REGISTERS; segmented softmax is
// per-lane predicated passes + 2x shfl_xor(16,32) over the quad group.
// ---------------------------------------------------------------------------
__global__ __launch_bounds__(256) void attn_k(
    const u16* __restrict__ Q, const u16* __restrict__ Kws,
    const u16* __restrict__ VT, u16* __restrict__ O) {
  const int s0 = blockIdx.x * 64;
  const int h  = blockIdx.y;
  const int b  = blockIdx.z;
  const int tid = threadIdx.x;
  const int w = tid >> 6, lane = tid & 63, l15 = lane & 15, quad = lane >> 4;

  __shared__ __align__(16) u16 KP[8192];  // K tiles (7168 used), then reused as P
  __shared__ __align__(16) u16 Vt[8192];  // V^T

  // stage K: [key<112][d<64]
  for (int e = tid; e < 7168; e += 256) {
    const int key = e >> 6, d = e & 63;
    u16 v = 0;
    if (key < 101) v = Kws[((size_t)b * 101 + key) * 1280 + h * 64 + d];
    const int off = ((key >> 4) * 2 + (d >> 5)) * 512 + ((d >> 3) & 3) * 128 + (key & 15) * 8 + (d & 7);
    KP[off] = v;
  }
  // stage V^T: [d<64][key<128]
  for (int e = tid; e < 8192; e += 256) {
    const int d = e >> 7, key = e & 127;
    u16 v = 0;
    if (key < 101) v = VT[((size_t)(b * 20 + h) * 64 + d) * 128 + key];
    const int off = ((d >> 4) * 4 + (key >> 5)) * 512 + ((key >> 3) & 3) * 128 + (d & 15) * 8 + (key & 7);
    Vt[off] = v;
  }
  // Q fragments straight from global (B-operand: n=l15 -> query, k=quad*8+j)
  const u16* qrow = Q + ((size_t)b * 4096 + s0 + w * 16 + l15) * 1280 + h * 64;
  const short8 qf0 = *(const short8*)(qrow + quad * 8);
  const short8 qf1 = *(const short8*)(qrow + 32 + quad * 8);
  __syncthreads();

  // S^T = K Q^T (7 key-tiles x 2 k-steps). D: col=l15=query, row=quad*4+r=key.
  f32x4 sc[7];
#pragma unroll
  for (int t = 0; t < 7; t++) {
    f32x4 a = (f32x4){0.f, 0.f, 0.f, 0.f};
    const short8 k0 = *(const short8*)(KP + (t * 2 + 0) * 512 + quad * 128 + l15 * 8);
    const short8 k1 = *(const short8*)(KP + (t * 2 + 1) * 512 + quad * 128 + l15 * 8);
    a = MFMA16(k0, qf0, a, 0, 0, 0);
    a = MFMA16(k1, qf1, a, 0, 0, 0);
    sc[t] = a;
  }

  // ---- segmented softmax, fully in registers ----
  float sv[7][4];
#pragma unroll
  for (int t = 0; t < 7; t++)
#pragma unroll
    for (int r = 0; r < 4; r++) sv[t][r] = sc[t][r] * 0.125f;

  const int kb = quad * 4;
  float mx0 = -1e30f, mx1 = -1e30f, mx2 = -1e30f, mx3 = -1e30f;
#pragma unroll
  for (int t = 0; t < 7; t++)
#pragma unroll
    for (int r = 0; r < 4; r++) {
      const int key = t * 16 + kb + r;
      const float v = sv[t][r];
      if (key < 77)       mx0 = fmaxf(mx0, v);
      else if (key < 81)  mx1 = fmaxf(mx1, v);
      else if (key < 85)  mx2 = fmaxf(mx2, v);
      else if (key < 101) mx3 = fmaxf(mx3, v);
    }
  mx0 = fmaxf(mx0, __shfl_xor(mx0, 16, 64)); mx0 = fmaxf(mx0, __shfl_xor(mx0, 32, 64));
  mx1 = fmaxf(mx1, __shfl_xor(mx1, 16, 64)); mx1 = fmaxf(mx1, __shfl_xor(mx1, 32, 64));
  mx2 = fmaxf(mx2, __shfl_xor(mx2, 16, 64)); mx2 = fmaxf(mx2, __shfl_xor(mx2, 32, 64));
  mx3 = fmaxf(mx3, __shfl_xor(mx3, 16, 64)); mx3 = fmaxf(mx3, __shfl_xor(mx3, 32, 64));

  float sm0 = 0.f, sm1 = 0.f, sm2 = 0.f, sm3 = 0.f;
#pragma unroll
  for (int t = 0; t < 7; t++)
#pragma unroll
    for (int r = 0; r < 4; r++) {
      const int key = t * 16 + kb + r;
      float e = 0.f;
      if (key < 77)       { e = __expf(sv[t][r] - mx0); sm0 += e; }
      else if (key < 81)  { e = __expf(sv[t][r] - mx1); sm1 += e; }
      else if (key < 85)  { e = __expf(sv[t][r] - mx2); sm2 += e; }
      else if (key < 101) { e = __expf(sv[t][r] - mx3); sm3 += e; }
      sv[t][r] = e;   // pads (key>=101) stay 0
    }
  sm0 += __shfl_xor(sm0, 16, 64); sm0 += __shfl_xor(sm0, 32, 64);
  sm1 += __shfl_xor(sm1, 16, 64); sm1 += __shfl_xor(sm1, 32, 64);
  sm2 += __shfl_xor(sm2, 16, 64); sm2 += __shfl_xor(sm2, 32, 64);
  sm3 += __shfl_xor(sm3, 16, 64); sm3 += __shfl_xor(sm3, 32, 64);
  const float inv0 = 1.f / sm0, inv1 = 1.f / sm1, inv2 = 1.f / sm2, inv3 = 1.f / sm3;
#pragma unroll
  for (int t = 0; t < 7; t++)
#pragma unroll
    for (int r = 0; r < 4; r++) {
      const int key = t * 16 + kb + r;
      const float f = key < 77 ? inv0 : key < 81 ? inv1 : key < 85 ? inv2 : inv3;
      sv[t][r] *= f;
    }

  // all waves' K-tile reads must finish before P overwrites KP
  __syncthreads();

  // write P (bf16) into KP in the PV A-operand frag layout for wave w
#pragma unroll
  for (int t = 0; t < 7; t++) {
    const int key0 = t * 16 + kb;
    const int off = (w * 4 + (key0 >> 5)) * 512 + ((key0 >> 3) & 3) * 128 + l15 * 8 + (key0 & 7);
    short4b pv;
    pv[0] = (short)f2b(sv[t][0]); pv[1] = (short)f2b(sv[t][1]);
    pv[2] = (short)f2b(sv[t][2]); pv[3] = (short)f2b(sv[t][3]);
    *(short4b*)(KP + off) = pv;
  }
  // zero pad keys 112..127 (ks=3 upper chunks)
  if (quad < 2)
    *(short8*)(KP + (w * 4 + 3) * 512 + (quad + 2) * 128 + l15 * 8) =
        (short8){0, 0, 0, 0, 0, 0, 0, 0};

  // O = P V  (4 k-steps x 4 d-tiles); same-wave P write->read ordered by lgkmcnt
  f32x4 oacc[4];
#pragma unroll
  for (int dsm = 0; dsm < 4; dsm++) oacc[dsm] = (f32x4){0.f, 0.f, 0.f, 0.f};
#pragma unroll
  for (int ks = 0; ks < 4; ks++) {
    const short8 pf = *(const short8*)(KP + (w * 4 + ks) * 512 + quad * 128 + l15 * 8);
#pragma unroll
    for (int dsm = 0; dsm < 4; dsm++) {
      const short8 vf = *(const short8*)(Vt + (dsm * 4 + ks) * 512 + quad * 128 + l15 * 8);
      oacc[dsm] = MFMA16(pf, vf, oacc[dsm], 0, 0, 0);
    }
  }
  u16* orow = O + ((size_t)b * 4096 + s0 + w * 16) * 1280 + h * 64;
#pragma unroll
  for (int dsm = 0; dsm < 4; dsm++)
#pragma unroll
    for (int r = 0; r < 4; r++)
      orow[(size_t)(quad * 4 + r) * 1280 + dsm * 16 + l15] = f2b(oacc[dsm][r]);
}

// ---------------------------------------------------------------------------
extern "C" void kernel_launch(void* const* d_in, const int* in_sizes, int n_in,
                              void* d_out, int out_size, void* d_ws, size_t ws_size,
                              hipStream_t stream) {
  const float* HS  = (const float*)d_in[0];   // [2][4096][1280] fp32
  const float* EHS = (const float*)d_in[1];   // [2][101][2048]  fp32
  const float* Wq  = (const float*)d_in[2];
  const float* Wo  = (const float*)d_in[11];
  const float* Bo  = (const float*)d_in[12];

  // workspace: ~28.7 MB. HSb aliases AO (HSb dead after Q-GEMM);
  // Qb (bf16 scratch) lives inside the fp32 d_out (dead before final write).
  u16* ws = (u16*)d_ws;
  u16* HSb  = ws;                      ws += (size_t)8192 * 1280;
  u16* AO   = HSb;
  u16* WqT  = ws;                      ws += (size_t)1280 * 1280;
  u16* WoT  = ws;                      ws += (size_t)1280 * 1280;
  u16* Kws  = ws;                      ws += (size_t)2 * 101 * 1280;
  u16* VTw  = ws;                      ws += (size_t)2 * 20 * 64 * 128;
  u16* Qb   = (u16*)d_out;
  (void)ws_size; (void)in_sizes; (void)n_in; (void)out_size;

  // fp32 -> bf16 hidden states
  cvt_k<<<dim3(8192 * 1280 / 4 / 256), 256, 0, stream>>>(HS, HSb, 8192 * 1280);

  // Wq / Wo transpose (+convert)
  TransArgs ta;
  ta.src[0] = Wq; ta.dst[0] = WqT;
  ta.src[1] = Wo; ta.dst[1] = WoT;
  transpose_k<<<dim3(20, 20, 2), dim3(64, 8), 0, stream>>>(ta);

  // Q projection (bf16 out, into d_out scratch)
  gemm_bt<false><<<dim3(64, 10), 256, 0, stream>>>(HSb, WqT, Qb, nullptr,
                                                   8192, 1280, 1280, nullptr, nullptr);

  // KV projections (fp32 inputs read directly); LDS-staged wide loads
  KVArgs ka;
  ka.ehs = EHS;
  for (int i = 0; i < 8; i++) ka.w[i] = (const float*)d_in[3 + i];
  ka.Kws = Kws; ka.VTws = VTw;
  kv_proj<<<dim3(32, 20), 256, 0, stream>>>(ka);

  // fused segmented attention (AO overwrites dead HSb)
  attn_k<<<dim3(64, 20, 2), 256, 0, stream>>>(Qb, Kws, VTw, AO);

  // out projection + bias + residual -> fp32 d_out (overwrites dead Qb)
  gemm_bt<true><<<dim3(64, 10), 256, 0, stream>>>(AO, WoT, nullptr, (float*)d_out,
                                                  8192, 1280, 1280, Bo, HS);
}

// Round 6
// 348.772 us; speedup vs baseline: 1.1795x; 1.0592x over previous
//
#include <hip/hip_runtime.h>
#include <stdint.h>

typedef unsigned short u16;
typedef __attribute__((ext_vector_type(8))) short short8;
typedef __attribute__((ext_vector_type(4))) short short4b;
typedef __attribute__((ext_vector_type(4))) float f32x4;

#define MFMA16 __builtin_amdgcn_mfma_f32_16x16x32_bf16

__device__ __forceinline__ u16 f2b(float f) {
  union { float f; uint32_t i; } x; x.f = f;
  uint32_t r = x.i + 0x7FFFu + ((x.i >> 16) & 1u);
  return (u16)(r >> 16);
}
__device__ __forceinline__ float b2f(u16 u) {
  union { uint32_t i; float f; } x; x.i = ((uint32_t)u) << 16; return x.f;
}

// async global->LDS, 16B per lane. HW semantics: LDS dest = wave-uniform
// base (lane0's value) + lane*16; global src is per-lane.
__device__ __forceinline__ void gload16(const u16* g, u16* l) {
  __builtin_amdgcn_global_load_lds(
      (const __attribute__((address_space(1))) void*)g,
      (__attribute__((address_space(3))) void*)l, 16, 0, 0);
}

// ---------------------------------------------------------------------------
// fp32 -> bf16 convert (n divisible by 4)
// ---------------------------------------------------------------------------
__global__ __launch_bounds__(256) void cvt_k(const float* __restrict__ src,
                                             u16* __restrict__ dst, int n) {
  const int i = (blockIdx.x * 256 + threadIdx.x) * 4;
  if (i < n) {
    const float4 v = *(const float4*)(src + i);
    dst[i + 0] = f2b(v.x); dst[i + 1] = f2b(v.y);
    dst[i + 2] = f2b(v.z); dst[i + 3] = f2b(v.w);
  }
}

// ---------------------------------------------------------------------------
// Weight transpose + convert: src fp32 [1280][1280] -> dst bf16 transposed
// ---------------------------------------------------------------------------
struct TransArgs { const float* src[2]; u16* dst[2]; };

__global__ __launch_bounds__(512) void transpose_k(TransArgs a) {
  const int m = blockIdx.z;
  const int r0 = blockIdx.y * 64;
  const int c0 = blockIdx.x * 64;
  const float* src = a.src[m];
  u16* dst = a.dst[m];
  __shared__ u16 t[64][65];
  const int tx = threadIdx.x, ty = threadIdx.y;   // 64 x 8
#pragma unroll
  for (int i = 0; i < 64; i += 8)
    t[ty + i][tx] = f2b(src[(size_t)(r0 + ty + i) * 1280 + c0 + tx]);
  __syncthreads();
#pragma unroll
  for (int i = 0; i < 64; i += 8)
    dst[(size_t)(c0 + ty + i) * 1280 + r0 + tx] = t[tx][ty + i];
}

// ---------------------------------------------------------------------------
// GEMM: C[M][N] = A[M][K] @ B[K][N], A/BT bf16, fp32 acc. BT[N][K].
// m97 structure — 128x128 tile, BK=64, 4 waves (each 64x64),
// global_load_lds width=16 staging, single-buffered, 2 barriers/K-tile.
// LDS layout: row-major [128][64] u16 with k-octet XOR swizzle:
//   element (row, k) at row*64 + ((k>>3) ^ (row&7))*8 + (k&7).
// Staging source pre-applies the same XOR (involution), so each row's 128B
// stays contiguous in global (fully coalesced) and LDS writes are linear.
// F32OUT: writes fp32 with fused +bias[N]+resid[M][N]; else bf16.
// ---------------------------------------------------------------------------
template <bool F32OUT>
__global__ __launch_bounds__(256) void gemm_bt(
    const u16* __restrict__ A, const u16* __restrict__ BT,
    u16* __restrict__ C16, float* __restrict__ C32,
    int M, int N, int K,
    const float* __restrict__ bias, const float* __restrict__ resid) {
  __shared__ __align__(16) u16 As[8192];   // 128 rows x 64 k
  __shared__ __align__(16) u16 Bs[8192];
  const int tid = threadIdx.x;
  const int w = tid >> 6, lane = tid & 63;
  const int l15 = lane & 15, quad = lane >> 4;
  const int m0 = blockIdx.x * 128, n0 = blockIdx.y * 128;
  const int wm = w >> 1, wn = w & 1;

  // staging addressing: call s (s=0..3) covers u16 [s*2048, s*2048+2048).
  // thread tid -> row = s*32 + (tid>>3), lds chunk = tid&7,
  // global chunk = (tid&7) ^ (row&7)  (s*32 = 0 mod 8).
  const int rowa = tid >> 3;
  const int cgx = (tid & 7) ^ (rowa & 7);
  const u16* pa = A  + (size_t)(m0 + rowa) * K + cgx * 8;
  const u16* pb = BT + (size_t)(n0 + rowa) * K + cgx * 8;
  u16* la = As + tid * 8;
  u16* lb = Bs + tid * 8;

  f32x4 acc[4][4];
#pragma unroll
  for (int i = 0; i < 4; i++)
#pragma unroll
    for (int j = 0; j < 4; j++) acc[i][j] = (f32x4){0.f, 0.f, 0.f, 0.f};

  for (int kt = 0; kt < K; kt += 64) {
#pragma unroll
    for (int s = 0; s < 4; s++) {
      const size_t go = (size_t)(s * 32) * K + kt;
      gload16(pa + go, la + s * 2048);
      gload16(pb + go, lb + s * 2048);
    }
    __syncthreads();   // compiler drains vmcnt(0) before s_barrier

#pragma unroll
    for (int ks = 0; ks < 2; ks++) {
      short8 af[4], bfr[4];
#pragma unroll
      for (int i = 0; i < 4; i++) {
        const int arow = wm * 64 + i * 16 + l15;
        const int brow = wn * 64 + i * 16 + l15;
        const int ch = ((ks * 4 + quad) ^ (l15 & 7)) * 8;
        af[i]  = *(const short8*)(As + arow * 64 + ch);
        bfr[i] = *(const short8*)(Bs + brow * 64 + ch);
      }
#pragma unroll
      for (int i = 0; i < 4; i++)
#pragma unroll
        for (int j = 0; j < 4; j++)
          acc[i][j] = MFMA16(af[i], bfr[j], acc[i][j], 0, 0, 0);
    }
    __syncthreads();   // frag reads done before next tile overwrites
  }

#pragma unroll
  for (int i = 0; i < 4; i++) {
    const int row0 = m0 + wm * 64 + i * 16 + quad * 4;
#pragma unroll
    for (int j = 0; j < 4; j++) {
      const int col = n0 + wn * 64 + j * 16 + l15;
      const float bv2 = F32OUT ? bias[col] : 0.f;
#pragma unroll
      for (int r = 0; r < 4; r++) {
        const size_t idx = (size_t)(row0 + r) * N + col;
        if (F32OUT) {
          C32[idx] = acc[i][j][r] + bv2 + resid[idx];
        } else {
          C16[idx] = f2b(acc[i][j][r]);
        }
      }
    }
  }
}

// ---------------------------------------------------------------------------
// KV projection. LDS-staged wide loads (R5 structure, proven).
// ---------------------------------------------------------------------------
struct KVArgs {
  const float* ehs;      // fp32 [2][101][2048]
  const float* w[8];     // fp32 [2048][1280]: k_txt,v_txt,k_obj,v_obj,k_oth,v_oth,k_ip,v_ip
  u16* Kws;              // bf16 [2][101][1280]
  u16* VTws;             // bf16 [2][20][64][128]
};

__global__ __launch_bounds__(256) void kv_proj(KVArgs a) {
  const int bx = blockIdx.x;          // 0..31
  const int b = bx >> 4;
  const int r = bx & 15;
  int mat, mt;
  if (r < 5)       { mat = 0; mt = r; }
  else if (r < 10) { mat = 1; mt = r - 5; }
  else             { mat = 2 + (r - 10); mt = 0; }
  const int seg = mat >> 1;
  const int soff4[4] = {0, 77, 81, 85};
  const int slen4[4] = {77, 4, 4, 16};
  const int soff = soff4[seg], slen = slen4[seg];
  const int n0 = blockIdx.y * 64;
  const int tid = threadIdx.x;
  const int w = tid >> 6;             // wave id: 16-col chunk
  const int lane = tid & 63, l15 = lane & 15, quad = lane >> 4;
  const float* W = a.w[mat];

  __shared__ __align__(16) u16 Wt[4096];  // [64 col][64 k] swizzled bf16
  __shared__ __align__(16) u16 At[1024];  // [16 tok][64 k] swizzled bf16

  // A staging map: thread -> (token row, k-float4)
  const int ar = tid >> 4, af4 = tid & 15;
  int tok = mt * 16 + ar; if (tok >= slen) tok = slen - 1;   // clamp (masked at store)
  const float* Arow = a.ehs + ((size_t)b * 101 + soff + tok) * 2048;

  float4 wreg[4]; float4 areg;
  // preload tile 0
#pragma unroll
  for (int rep = 0; rep < 4; rep++) {
    const int idx = rep * 256 + tid;
    const int kr = idx >> 4, f4 = idx & 15;
    wreg[rep] = *(const float4*)(W + (size_t)kr * 1280 + n0 + f4 * 4);
  }
  areg = *(const float4*)(Arow + af4 * 4);

  f32x4 acc = (f32x4){0.f, 0.f, 0.f, 0.f};
  const int colw = w * 16 + l15;                 // wave's col within the 64-chunk
  const int colp = (colw + (colw >> 3)) & 7;     // col-spread swizzle class

  for (int t = 0; t < 32; ++t) {
    // write staged regs -> LDS (transpose W on the fly)
#pragma unroll
    for (int rep = 0; rep < 4; rep++) {
      const int idx = rep * 256 + tid;
      const int kr = idx >> 4, f4 = idx & 15;
      const float wsv[4] = {wreg[rep].x, wreg[rep].y, wreg[rep].z, wreg[rep].w};
#pragma unroll
      for (int i = 0; i < 4; i++) {
        const int col = f4 * 4 + i;
        const int oct = (kr >> 3) ^ ((col + (col >> 3)) & 7);
        Wt[col * 64 + oct * 8 + (kr & 7)] = f2b(wsv[i]);
      }
    }
    {
      short4b av4;
      av4[0] = (short)f2b(areg.x); av4[1] = (short)f2b(areg.y);
      av4[2] = (short)f2b(areg.z); av4[3] = (short)f2b(areg.w);
      *(short4b*)(At + ar * 64 + (((af4 >> 1) ^ (ar & 7)) * 8) + (af4 & 1) * 4) = av4;
    }
    __syncthreads();

    // issue next-tile global loads (land during compute; consumed next iter)
    if (t + 1 < 32) {
      const int k0 = (t + 1) * 64;
#pragma unroll
      for (int rep = 0; rep < 4; rep++) {
        const int idx = rep * 256 + tid;
        const int kr = idx >> 4, f4 = idx & 15;
        wreg[rep] = *(const float4*)(W + (size_t)(k0 + kr) * 1280 + n0 + f4 * 4);
      }
      areg = *(const float4*)(Arow + k0 + af4 * 4);
    }

    // compute from LDS: 2 k-steps of 32
#pragma unroll
    for (int ks = 0; ks < 2; ks++) {
      const short8 af = *(const short8*)(At + l15 * 64 + (((ks * 4 + quad) ^ (l15 & 7)) * 8));
      const short8 bf = *(const short8*)(Wt + colw * 64 + (((ks * 4 + quad) ^ colp) * 8));
      acc = MFMA16(af, bf, acc, 0, 0, 0);
    }
    __syncthreads();   // reads done before next tile's LDS writes
  }

  const bool isK = !(mat & 1);
#pragma unroll
  for (int rr = 0; rr < 4; rr++) {
    const int tloc = mt * 16 + quad * 4 + rr;
    if (tloc >= slen) continue;
    const int key = soff + tloc;
    const int col = n0 + w * 16 + l15;
    const u16 v = f2b(acc[rr]);
    if (isK) {
      a.Kws[((size_t)b * 101 + key) * 1280 + col] = v;
    } else {
      const int hh = col >> 6, dd = col & 63;
      a.VTws[((size_t)(b * 20 + hh) * 64 + dd) * 128 + key] = v;
    }
  }
}

// ---------------------------------------------------------------------------
// Fused segmented attention. Block = (b, h, 64 queries), 4 waves.
// R6: K/V fragments read DIRECTLY from global (K/V total 845KB = L2-resident;
// LDS staging was pure overhead + 8-way ds_write conflicts — Common-mistake
// #7). LDS now holds only the 16KB P buffer, whose write->read is same-wave
// (per-wave disjoint 4KB chunks) -> ZERO barriers in the kernel.
// Requires VTws pad keys [101,128) to be zero: hipMemsetAsync in launcher.
//
// Swapped QK^T (mfma(K,Q)): lane holds its query's 28 scores in registers;
// segmented softmax per-lane + 2x shfl_xor(16,32) over the quad group.
// P LDS frag layout (per [64][128] tile): elem (q,key) at
// ((q/16)*4 + key/32)*512 + ((key%32)/8)*128 + (q%16)*8 + (key%8).
// ---------------------------------------------------------------------------
__global__ __launch_bounds__(256) void attn_k(
    const u16* __restrict__ Q, const u16* __restrict__ Kws,
    const u16* __restrict__ VT, u16* __restrict__ O) {
  const int s0 = blockIdx.x * 64;
  const int h  = blockIdx.y;
  const int b  = blockIdx.z;
  const int tid = threadIdx.x;
  const int w = tid >> 6, lane = tid & 63, l15 = lane & 15, quad = lane >> 4;

  __shared__ __align__(16) u16 P[8192];   // P fragments only (16KB)

  // Q fragments straight from global (B-operand: n=l15 -> query, k=quad*8+j)
  const u16* qrow = Q + ((size_t)b * 4096 + s0 + w * 16 + l15) * 1280 + h * 64;
  const short8 qf0 = *(const short8*)(qrow + quad * 8);
  const short8 qf1 = *(const short8*)(qrow + 32 + quad * 8);

  // S^T = K Q^T. A-operand K frag: m=l15 -> key row, k=quad*8+j -> d.
  // Tiles 0..5: keys t*16+l15 <= 95+15? (t=5: 80..95) all < 101, unconditional.
  // Tile 6: keys 96..111, predicated (rows >=101 are zero).
  const u16* kbase = Kws + (size_t)b * 101 * 1280 + h * 64;
  f32x4 sc[7];
#pragma unroll
  for (int t = 0; t < 6; t++) {
    const u16* krow = kbase + (size_t)(t * 16 + l15) * 1280 + quad * 8;
    const short8 k0 = *(const short8*)(krow);
    const short8 k1 = *(const short8*)(krow + 32);
    f32x4 a = (f32x4){0.f, 0.f, 0.f, 0.f};
    a = MFMA16(k0, qf0, a, 0, 0, 0);
    a = MFMA16(k1, qf1, a, 0, 0, 0);
    sc[t] = a;
  }
  {
    short8 k0 = (short8){0,0,0,0,0,0,0,0}, k1 = k0;
    if (96 + l15 < 101) {
      const u16* krow = kbase + (size_t)(96 + l15) * 1280 + quad * 8;
      k0 = *(const short8*)(krow);
      k1 = *(const short8*)(krow + 32);
    }
    f32x4 a = (f32x4){0.f, 0.f, 0.f, 0.f};
    a = MFMA16(k0, qf0, a, 0, 0, 0);
    a = MFMA16(k1, qf1, a, 0, 0, 0);
    sc[6] = a;
  }

  // ---- segmented softmax, fully in registers ----
  float sv[7][4];
#pragma unroll
  for (int t = 0; t < 7; t++)
#pragma unroll
    for (int r = 0; r < 4; r++) sv[t][r] = sc[t][r] * 0.125f;

  const int kb = quad * 4;
  float mx0 = -1e30f, mx1 = -1e30f, mx2 = -1e30f, mx3 = -1e30f;
#pragma unroll
  for (int t = 0; t < 7; t++)
#pragma unroll
    for (int r = 0; r < 4; r++) {
      const int key = t * 16 + kb + r;
      const float v = sv[t][r];
      if (key < 77)       mx0 = fmaxf(mx0, v);
      else if (key < 81)  mx1 = fmaxf(mx1, v);
      else if (key < 85)  mx2 = fmaxf(mx2, v);
      else if (key < 101) mx3 = fmaxf(mx3, v);
    }
  mx0 = fmaxf(mx0, __shfl_xor(mx0, 16, 64)); mx0 = fmaxf(mx0, __shfl_xor(mx0, 32, 64));
  mx1 = fmaxf(mx1, __shfl_xor(mx1, 16, 64)); mx1 = fmaxf(mx1, __shfl_xor(mx1, 32, 64));
  mx2 = fmaxf(mx2, __shfl_xor(mx2, 16, 64)); mx2 = fmaxf(mx2, __shfl_xor(mx2, 32, 64));
  mx3 = fmaxf(mx3, __shfl_xor(mx3, 16, 64)); mx3 = fmaxf(mx3, __shfl_xor(mx3, 32, 64));

  float sm0 = 0.f, sm1 = 0.f, sm2 = 0.f, sm3 = 0.f;
#pragma unroll
  for (int t = 0; t < 7; t++)
#pragma unroll
    for (int r = 0; r < 4; r++) {
      const int key = t * 16 + kb + r;
      float e = 0.f;
      if (key < 77)       { e = __expf(sv[t][r] - mx0); sm0 += e; }
      else if (key < 81)  { e = __expf(sv[t][r] - mx1); sm1 += e; }
      else if (key < 85)  { e = __expf(sv[t][r] - mx2); sm2 += e; }
      else if (key < 101) { e = __expf(sv[t][r] - mx3); sm3 += e; }
      sv[t][r] = e;   // pads (key>=101) stay 0
    }
  sm0 += __shfl_xor(sm0, 16, 64); sm0 += __shfl_xor(sm0, 32, 64);
  sm1 += __shfl_xor(sm1, 16, 64); sm1 += __shfl_xor(sm1, 32, 64);
  sm2 += __shfl_xor(sm2, 16, 64); sm2 += __shfl_xor(sm2, 32, 64);
  sm3 += __shfl_xor(sm3, 16, 64); sm3 += __shfl_xor(sm3, 32, 64);
  const float inv0 = 1.f / sm0, inv1 = 1.f / sm1, inv2 = 1.f / sm2, inv3 = 1.f / sm3;
#pragma unroll
  for (int t = 0; t < 7; t++)
#pragma unroll
    for (int r = 0; r < 4; r++) {
      const int key = t * 16 + kb + r;
      const float f = key < 77 ? inv0 : key < 81 ? inv1 : key < 85 ? inv2 : inv3;
      sv[t][r] *= f;
    }

  // write P (bf16) into this wave's own P chunk (no cross-wave sharing)
#pragma unroll
  for (int t = 0; t < 7; t++) {
    const int key0 = t * 16 + kb;
    const int off = (w * 4 + (key0 >> 5)) * 512 + ((key0 >> 3) & 3) * 128 + l15 * 8 + (key0 & 7);
    short4b pv;
    pv[0] = (short)f2b(sv[t][0]); pv[1] = (short)f2b(sv[t][1]);
    pv[2] = (short)f2b(sv[t][2]); pv[3] = (short)f2b(sv[t][3]);
    *(short4b*)(P + off) = pv;
  }
  // zero pad keys 112..127 (ks=3 upper octets)
  if (quad < 2)
    *(short8*)(P + (w * 4 + 3) * 512 + (quad + 2) * 128 + l15 * 8) =
        (short8){0, 0, 0, 0, 0, 0, 0, 0};

  // O = P V: pf from LDS (same-wave, lgkmcnt-ordered), vf direct from global.
  // VT pad keys [101,128) are zeroed by the launcher memset.
  const u16* vbase = VT + (size_t)(b * 20 + h) * 64 * 128;
  f32x4 oacc[4];
#pragma unroll
  for (int dsm = 0; dsm < 4; dsm++) oacc[dsm] = (f32x4){0.f, 0.f, 0.f, 0.f};
#pragma unroll
  for (int ks = 0; ks < 4; ks++) {
    const short8 pf = *(const short8*)(P + (w * 4 + ks) * 512 + quad * 128 + l15 * 8);
#pragma unroll
    for (int dsm = 0; dsm < 4; dsm++) {
      const short8 vf = *(const short8*)(vbase + (size_t)(dsm * 16 + l15) * 128 + ks * 32 + quad * 8);
      oacc[dsm] = MFMA16(pf, vf, oacc[dsm], 0, 0, 0);
    }
  }
  u16* orow = O + ((size_t)b * 4096 + s0 + w * 16) * 1280 + h * 64;
#pragma unroll
  for (int dsm = 0; dsm < 4; dsm++)
#pragma unroll
    for (int r = 0; r < 4; r++)
      orow[(size_t)(quad * 4 + r) * 1280 + dsm * 16 + l15] = f2b(oacc[dsm][r]);
}

// ---------------------------------------------------------------------------
extern "C" void kernel_launch(void* const* d_in, const int* in_sizes, int n_in,
                              void* d_out, int out_size, void* d_ws, size_t ws_size,
                              hipStream_t stream) {
  const float* HS  = (const float*)d_in[0];   // [2][4096][1280] fp32
  const float* EHS = (const float*)d_in[1];   // [2][101][2048]  fp32
  const float* Wq  = (const float*)d_in[2];
  const float* Wo  = (const float*)d_in[11];
  const float* Bo  = (const float*)d_in[12];

  // workspace: ~28.7 MB. HSb aliases AO (HSb dead after Q-GEMM);
  // Qb (bf16 scratch) lives inside the fp32 d_out (dead before final write).
  u16* ws = (u16*)d_ws;
  u16* HSb  = ws;                      ws += (size_t)8192 * 1280;
  u16* AO   = HSb;
  u16* WqT  = ws;                      ws += (size_t)1280 * 1280;
  u16* WoT  = ws;                      ws += (size_t)1280 * 1280;
  u16* Kws  = ws;                      ws += (size_t)2 * 101 * 1280;
  u16* VTw  = ws;                      ws += (size_t)2 * 20 * 64 * 128;
  u16* Qb   = (u16*)d_out;
  (void)ws_size; (void)in_sizes; (void)n_in; (void)out_size;

  // zero VTw so pad keys [101,128) are 0 (attn reads them; 0*garbage->NaN risk)
  hipMemsetAsync(VTw, 0, (size_t)2 * 20 * 64 * 128 * sizeof(u16), stream);

  // fp32 -> bf16 hidden states
  cvt_k<<<dim3(8192 * 1280 / 4 / 256), 256, 0, stream>>>(HS, HSb, 8192 * 1280);

  // Wq / Wo transpose (+convert)
  TransArgs ta;
  ta.src[0] = Wq; ta.dst[0] = WqT;
  ta.src[1] = Wo; ta.dst[1] = WoT;
  transpose_k<<<dim3(20, 20, 2), dim3(64, 8), 0, stream>>>(ta);

  // Q projection (bf16 out, into d_out scratch)
  gemm_bt<false><<<dim3(64, 10), 256, 0, stream>>>(HSb, WqT, Qb, nullptr,
                                                   8192, 1280, 1280, nullptr, nullptr);

  // KV projections (fp32 inputs read directly); LDS-staged wide loads
  KVArgs ka;
  ka.ehs = EHS;
  for (int i = 0; i < 8; i++) ka.w[i] = (const float*)d_in[3 + i];
  ka.Kws = Kws; ka.VTws = VTw;
  kv_proj<<<dim3(32, 20), 256, 0, stream>>>(ka);

  // fused segmented attention (AO overwrites dead HSb)
  attn_k<<<dim3(64, 20, 2), 256, 0, stream>>>(Qb, Kws, VTw, AO);

  // out projection + bias + residual -> fp32 d_out (overwrites dead Qb)
  gemm_bt<true><<<dim3(64, 10), 256, 0, stream>>>(AO, WoT, nullptr, (float*)d_out,
                                                  8192, 1280, 1280, Bo, HS);
}

// Round 7
// 340.502 us; speedup vs baseline: 1.2082x; 1.0243x over previous
//
#include <hip/hip_runtime.h>
#include <stdint.h>

typedef unsigned short u16;
typedef __attribute__((ext_vector_type(8))) short short8;
typedef __attribute__((ext_vector_type(4))) short short4b;
typedef __attribute__((ext_vector_type(4))) float f32x4;

#define MFMA16 __builtin_amdgcn_mfma_f32_16x16x32_bf16

__device__ __forceinline__ u16 f2b(float f) {
  union { float f; uint32_t i; } x; x.f = f;
  uint32_t r = x.i + 0x7FFFu + ((x.i >> 16) & 1u);
  return (u16)(r >> 16);
}
__device__ __forceinline__ float b2f(u16 u) {
  union { uint32_t i; float f; } x; x.i = ((uint32_t)u) << 16; return x.f;
}

// async global->LDS, 16B per lane. HW semantics: LDS dest = wave-uniform
// base (lane0's value) + lane*16; global src is per-lane.
__device__ __forceinline__ void gload16(const u16* g, u16* l) {
  __builtin_amdgcn_global_load_lds(
      (const __attribute__((address_space(1))) void*)g,
      (__attribute__((address_space(3))) void*)l, 16, 0, 0);
}

// ---------------------------------------------------------------------------
// fp32 -> bf16 convert (n divisible by 4)
// ---------------------------------------------------------------------------
__global__ __launch_bounds__(256) void cvt_k(const float* __restrict__ src,
                                             u16* __restrict__ dst, int n) {
  const int i = (blockIdx.x * 256 + threadIdx.x) * 4;
  if (i < n) {
    const float4 v = *(const float4*)(src + i);
    dst[i + 0] = f2b(v.x); dst[i + 1] = f2b(v.y);
    dst[i + 2] = f2b(v.z); dst[i + 3] = f2b(v.w);
  }
}

// ---------------------------------------------------------------------------
// Weight transpose + convert: src fp32 [1280][1280] -> dst bf16 transposed
// ---------------------------------------------------------------------------
struct TransArgs { const float* src[2]; u16* dst[2]; };

__global__ __launch_bounds__(512) void transpose_k(TransArgs a) {
  const int m = blockIdx.z;
  const int r0 = blockIdx.y * 64;
  const int c0 = blockIdx.x * 64;
  const float* src = a.src[m];
  u16* dst = a.dst[m];
  __shared__ u16 t[64][65];
  const int tx = threadIdx.x, ty = threadIdx.y;   // 64 x 8
#pragma unroll
  for (int i = 0; i < 64; i += 8)
    t[ty + i][tx] = f2b(src[(size_t)(r0 + ty + i) * 1280 + c0 + tx]);
  __syncthreads();
#pragma unroll
  for (int i = 0; i < 64; i += 8)
    dst[(size_t)(c0 + ty + i) * 1280 + r0 + tx] = t[tx][ty + i];
}

// ---------------------------------------------------------------------------
// GEMM: C[M][N] = A[M][K] @ B[K][N], A/BT bf16, fp32 acc. BT[N][K].
// R7: 128x64 tile (was 128x128) -> grid 1280 blocks = 5/CU (was 2.5,
// grid-limited; the per-K-tile vmcnt-drain stall had no co-resident block
// to overlap with). 4 waves, each 32(M)x64(N), acc[2][4]. BK=64,
// global_load_lds width=16 staging, single-buffered, 2 barriers/K-tile.
// LDS layout unchanged: element (row, k) at row*64 + ((k>>3)^(row&7))*8 +
// (k&7); staging source pre-applies the XOR (involution).
// F32OUT: writes fp32 with fused +bias[N]+resid[M][N]; else bf16.
// ---------------------------------------------------------------------------
template <bool F32OUT>
__global__ __launch_bounds__(256) void gemm_bt(
    const u16* __restrict__ A, const u16* __restrict__ BT,
    u16* __restrict__ C16, float* __restrict__ C32,
    int M, int N, int K,
    const float* __restrict__ bias, const float* __restrict__ resid) {
  __shared__ __align__(16) u16 As[8192];   // 128 rows x 64 k
  __shared__ __align__(16) u16 Bs[4096];   // 64 rows x 64 k
  const int tid = threadIdx.x;
  const int w = tid >> 6, lane = tid & 63;
  const int l15 = lane & 15, quad = lane >> 4;
  const int m0 = blockIdx.x * 128, n0 = blockIdx.y * 64;

  // staging: call s covers rows s*32..s*32+31 (A: s=0..3, B: s=0..1).
  // thread tid -> row = s*32 + (tid>>3), lds chunk = tid&7,
  // global chunk = (tid&7) ^ (row&7)  (s*32 = 0 mod 8).
  const int rowa = tid >> 3;
  const int cgx = (tid & 7) ^ (rowa & 7);
  const u16* pa = A  + (size_t)(m0 + rowa) * K + cgx * 8;
  const u16* pb = BT + (size_t)(n0 + rowa) * K + cgx * 8;
  u16* la = As + tid * 8;
  u16* lb = Bs + tid * 8;

  f32x4 acc[2][4];
#pragma unroll
  for (int i = 0; i < 2; i++)
#pragma unroll
    for (int j = 0; j < 4; j++) acc[i][j] = (f32x4){0.f, 0.f, 0.f, 0.f};

  for (int kt = 0; kt < K; kt += 64) {
#pragma unroll
    for (int s = 0; s < 4; s++)
      gload16(pa + (size_t)(s * 32) * K + kt, la + s * 2048);
#pragma unroll
    for (int s = 0; s < 2; s++)
      gload16(pb + (size_t)(s * 32) * K + kt, lb + s * 2048);
    __syncthreads();   // compiler drains vmcnt(0) before s_barrier

#pragma unroll
    for (int ks = 0; ks < 2; ks++) {
      const int ch = ((ks * 4 + quad) ^ (l15 & 7)) * 8;
      short8 af[2], bfr[4];
#pragma unroll
      for (int i = 0; i < 2; i++)
        af[i] = *(const short8*)(As + (w * 32 + i * 16 + l15) * 64 + ch);
#pragma unroll
      for (int j = 0; j < 4; j++)
        bfr[j] = *(const short8*)(Bs + (j * 16 + l15) * 64 + ch);
#pragma unroll
      for (int i = 0; i < 2; i++)
#pragma unroll
        for (int j = 0; j < 4; j++)
          acc[i][j] = MFMA16(af[i], bfr[j], acc[i][j], 0, 0, 0);
    }
    __syncthreads();   // frag reads done before next tile overwrites
  }

#pragma unroll
  for (int i = 0; i < 2; i++) {
    const int row0 = m0 + w * 32 + i * 16 + quad * 4;
#pragma unroll
    for (int j = 0; j < 4; j++) {
      const int col = n0 + j * 16 + l15;
      const float bv2 = F32OUT ? bias[col] : 0.f;
#pragma unroll
      for (int r = 0; r < 4; r++) {
        const size_t idx = (size_t)(row0 + r) * N + col;
        if (F32OUT) {
          C32[idx] = acc[i][j][r] + bv2 + resid[idx];
        } else {
          C16[idx] = f2b(acc[i][j][r]);
        }
      }
    }
  }
}

// ---------------------------------------------------------------------------
// KV projection. R7: BK=128 (was 64) — 16 iterations, 10 float4 in flight
// per thread (160B, was 80B), half the barriers. Per-iter latency exposure
// was the limiter (prefetch window = tiny compute phase only).
// LDS: Wt [64 col][128 k], At [16 tok][128 k], both octet-XOR swizzled
// (4-bit octet index, XOR on low 3 bits, bijective per row/col).
// ---------------------------------------------------------------------------
struct KVArgs {
  const float* ehs;      // fp32 [2][101][2048]
  const float* w[8];     // fp32 [2048][1280]: k_txt,v_txt,k_obj,v_obj,k_oth,v_oth,k_ip,v_ip
  u16* Kws;              // bf16 [2][101][1280]
  u16* VTws;             // bf16 [2][20][64][128]
};

__global__ __launch_bounds__(256) void kv_proj(KVArgs a) {
  const int bx = blockIdx.x;          // 0..31
  const int b = bx >> 4;
  const int r = bx & 15;
  int mat, mt;
  if (r < 5)       { mat = 0; mt = r; }
  else if (r < 10) { mat = 1; mt = r - 5; }
  else             { mat = 2 + (r - 10); mt = 0; }
  const int seg = mat >> 1;
  const int soff4[4] = {0, 77, 81, 85};
  const int slen4[4] = {77, 4, 4, 16};
  const int soff = soff4[seg], slen = slen4[seg];
  const int n0 = blockIdx.y * 64;
  const int tid = threadIdx.x;
  const int w = tid >> 6;             // wave id: 16-col chunk
  const int lane = tid & 63, l15 = lane & 15, quad = lane >> 4;
  const float* W = a.w[mat];

  __shared__ __align__(16) u16 Wt[8192];  // [64 col][128 k] swizzled bf16
  __shared__ __align__(16) u16 At[2048];  // [16 tok][128 k] swizzled bf16

  // staging maps: W: thread+rep -> (kr = rep*16 + tid>>4, col group f4 = tid&15)
  //               A: thread -> (token ar = tid>>4, k-группа af4 = tid&15, 2 halves)
  const int ar = tid >> 4, af4 = tid & 15;
  int tok = mt * 16 + ar; if (tok >= slen) tok = slen - 1;   // clamp (masked at store)
  const float* Arow = a.ehs + ((size_t)b * 101 + soff + tok) * 2048;

  float4 wreg[8]; float4 areg[2];
  // preload tile 0
#pragma unroll
  for (int rep = 0; rep < 8; rep++) {
    const int kr = rep * 16 + (tid >> 4);
    wreg[rep] = *(const float4*)(W + (size_t)kr * 1280 + n0 + af4 * 4);
  }
  areg[0] = *(const float4*)(Arow + af4 * 4);
  areg[1] = *(const float4*)(Arow + 64 + af4 * 4);

  f32x4 acc = (f32x4){0.f, 0.f, 0.f, 0.f};
  const int colw = w * 16 + l15;                 // wave's col within the 64-chunk
  const int colp = (colw + (colw >> 3)) & 7;     // col-spread swizzle class

  for (int t = 0; t < 16; ++t) {
    // write staged regs -> LDS (transpose W on the fly)
#pragma unroll
    for (int rep = 0; rep < 8; rep++) {
      const int kr = rep * 16 + (tid >> 4);
      const float wsv[4] = {wreg[rep].x, wreg[rep].y, wreg[rep].z, wreg[rep].w};
#pragma unroll
      for (int i = 0; i < 4; i++) {
        const int col = af4 * 4 + i;
        const int oct = (kr >> 3) ^ ((col + (col >> 3)) & 7);
        Wt[col * 128 + oct * 8 + (kr & 7)] = f2b(wsv[i]);
      }
    }
#pragma unroll
    for (int h = 0; h < 2; h++) {
      short4b av4;
      av4[0] = (short)f2b(areg[h].x); av4[1] = (short)f2b(areg[h].y);
      av4[2] = (short)f2b(areg[h].z); av4[3] = (short)f2b(areg[h].w);
      const int oct = (h * 8 + (af4 >> 1)) ^ (ar & 7);
      *(short4b*)(At + ar * 128 + oct * 8 + (af4 & 1) * 4) = av4;
    }
    __syncthreads();

    // issue next-tile global loads (land during compute; consumed next iter)
    if (t + 1 < 16) {
      const int k0 = (t + 1) * 128;
#pragma unroll
      for (int rep = 0; rep < 8; rep++) {
        const int kr = rep * 16 + (tid >> 4);
        wreg[rep] = *(const float4*)(W + (size_t)(k0 + kr) * 1280 + n0 + af4 * 4);
      }
      areg[0] = *(const float4*)(Arow + k0 + af4 * 4);
      areg[1] = *(const float4*)(Arow + k0 + 64 + af4 * 4);
    }

    // compute from LDS: 4 k-steps of 32
#pragma unroll
    for (int ks = 0; ks < 4; ks++) {
      const short8 af = *(const short8*)(At + l15 * 128 + (((ks * 4 + quad) ^ (l15 & 7)) * 8));
      const short8 bf = *(const short8*)(Wt + colw * 128 + (((ks * 4 + quad) ^ colp) * 8));
      acc = MFMA16(af, bf, acc, 0, 0, 0);
    }
    __syncthreads();   // reads done before next tile's LDS writes
  }

  const bool isK = !(mat & 1);
#pragma unroll
  for (int rr = 0; rr < 4; rr++) {
    const int tloc = mt * 16 + quad * 4 + rr;
    if (tloc >= slen) continue;
    const int key = soff + tloc;
    const int col = n0 + w * 16 + l15;
    const u16 v = f2b(acc[rr]);
    if (isK) {
      a.Kws[((size_t)b * 101 + key) * 1280 + col] = v;
    } else {
      const int hh = col >> 6, dd = col & 63;
      a.VTws[((size_t)(b * 20 + hh) * 64 + dd) * 128 + key] = v;
    }
  }
}

// ---------------------------------------------------------------------------
// Fused segmented attention. Block = (b, h, 64 queries), 4 waves.
// K/V fragments read DIRECTLY from global (L2-resident); LDS holds only the
// 16KB P buffer (same-wave write->read) -> zero barriers.
// Requires VTws pad keys [101,128) zeroed (launcher memset).
// ---------------------------------------------------------------------------
__global__ __launch_bounds__(256) void attn_k(
    const u16* __restrict__ Q, const u16* __restrict__ Kws,
    const u16* __restrict__ VT, u16* __restrict__ O) {
  const int s0 = blockIdx.x * 64;
  const int h  = blockIdx.y;
  const int b  = blockIdx.z;
  const int tid = threadIdx.x;
  const int w = tid >> 6, lane = tid & 63, l15 = lane & 15, quad = lane >> 4;

  __shared__ __align__(16) u16 P[8192];   // P fragments only (16KB)

  // Q fragments straight from global (B-operand: n=l15 -> query, k=quad*8+j)
  const u16* qrow = Q + ((size_t)b * 4096 + s0 + w * 16 + l15) * 1280 + h * 64;
  const short8 qf0 = *(const short8*)(qrow + quad * 8);
  const short8 qf1 = *(const short8*)(qrow + 32 + quad * 8);

  // S^T = K Q^T. A-operand K frag: m=l15 -> key row, k=quad*8+j -> d.
  const u16* kbase = Kws + (size_t)b * 101 * 1280 + h * 64;
  f32x4 sc[7];
#pragma unroll
  for (int t = 0; t < 6; t++) {
    const u16* krow = kbase + (size_t)(t * 16 + l15) * 1280 + quad * 8;
    const short8 k0 = *(const short8*)(krow);
    const short8 k1 = *(const short8*)(krow + 32);
    f32x4 a = (f32x4){0.f, 0.f, 0.f, 0.f};
    a = MFMA16(k0, qf0, a, 0, 0, 0);
    a = MFMA16(k1, qf1, a, 0, 0, 0);
    sc[t] = a;
  }
  {
    short8 k0 = (short8){0,0,0,0,0,0,0,0}, k1 = k0;
    if (96 + l15 < 101) {
      const u16* krow = kbase + (size_t)(96 + l15) * 1280 + quad * 8;
      k0 = *(const short8*)(krow);
      k1 = *(const short8*)(krow + 32);
    }
    f32x4 a = (f32x4){0.f, 0.f, 0.f, 0.f};
    a = MFMA16(k0, qf0, a, 0, 0, 0);
    a = MFMA16(k1, qf1, a, 0, 0, 0);
    sc[6] = a;
  }

  // ---- segmented softmax, fully in registers ----
  float sv[7][4];
#pragma unroll
  for (int t = 0; t < 7; t++)
#pragma unroll
    for (int r = 0; r < 4; r++) sv[t][r] = sc[t][r] * 0.125f;

  const int kb = quad * 4;
  float mx0 = -1e30f, mx1 = -1e30f, mx2 = -1e30f, mx3 = -1e30f;
#pragma unroll
  for (int t = 0; t < 7; t++)
#pragma unroll
    for (int r = 0; r < 4; r++) {
      const int key = t * 16 + kb + r;
      const float v = sv[t][r];
      if (key < 77)       mx0 = fmaxf(mx0, v);
      else if (key < 81)  mx1 = fmaxf(mx1, v);
      else if (key < 85)  mx2 = fmaxf(mx2, v);
      else if (key < 101) mx3 = fmaxf(mx3, v);
    }
  mx0 = fmaxf(mx0, __shfl_xor(mx0, 16, 64)); mx0 = fmaxf(mx0, __shfl_xor(mx0, 32, 64));
  mx1 = fmaxf(mx1, __shfl_xor(mx1, 16, 64)); mx1 = fmaxf(mx1, __shfl_xor(mx1, 32, 64));
  mx2 = fmaxf(mx2, __shfl_xor(mx2, 16, 64)); mx2 = fmaxf(mx2, __shfl_xor(mx2, 32, 64));
  mx3 = fmaxf(mx3, __shfl_xor(mx3, 16, 64)); mx3 = fmaxf(mx3, __shfl_xor(mx3, 32, 64));

  float sm0 = 0.f, sm1 = 0.f, sm2 = 0.f, sm3 = 0.f;
#pragma unroll
  for (int t = 0; t < 7; t++)
#pragma unroll
    for (int r = 0; r < 4; r++) {
      const int key = t * 16 + kb + r;
      float e = 0.f;
      if (key < 77)       { e = __expf(sv[t][r] - mx0); sm0 += e; }
      else if (key < 81)  { e = __expf(sv[t][r] - mx1); sm1 += e; }
      else if (key < 85)  { e = __expf(sv[t][r] - mx2); sm2 += e; }
      else if (key < 101) { e = __expf(sv[t][r] - mx3); sm3 += e; }
      sv[t][r] = e;   // pads (key>=101) stay 0
    }
  sm0 += __shfl_xor(sm0, 16, 64); sm0 += __shfl_xor(sm0, 32, 64);
  sm1 += __shfl_xor(sm1, 16, 64); sm1 += __shfl_xor(sm1, 32, 64);
  sm2 += __shfl_xor(sm2, 16, 64); sm2 += __shfl_xor(sm2, 32, 64);
  sm3 += __shfl_xor(sm3, 16, 64); sm3 += __shfl_xor(sm3, 32, 64);
  const float inv0 = 1.f / sm0, inv1 = 1.f / sm1, inv2 = 1.f / sm2, inv3 = 1.f / sm3;
#pragma unroll
  for (int t = 0; t < 7; t++)
#pragma unroll
    for (int r = 0; r < 4; r++) {
      const int key = t * 16 + kb + r;
      const float f = key < 77 ? inv0 : key < 81 ? inv1 : key < 85 ? inv2 : inv3;
      sv[t][r] *= f;
    }

  // write P (bf16) into this wave's own P chunk (no cross-wave sharing)
#pragma unroll
  for (int t = 0; t < 7; t++) {
    const int key0 = t * 16 + kb;
    const int off = (w * 4 + (key0 >> 5)) * 512 + ((key0 >> 3) & 3) * 128 + l15 * 8 + (key0 & 7);
    short4b pv;
    pv[0] = (short)f2b(sv[t][0]); pv[1] = (short)f2b(sv[t][1]);
    pv[2] = (short)f2b(sv[t][2]); pv[3] = (short)f2b(sv[t][3]);
    *(short4b*)(P + off) = pv;
  }
  // zero pad keys 112..127 (ks=3 upper octets)
  if (quad < 2)
    *(short8*)(P + (w * 4 + 3) * 512 + (quad + 2) * 128 + l15 * 8) =
        (short8){0, 0, 0, 0, 0, 0, 0, 0};

  // O = P V: pf from LDS (same-wave, lgkmcnt-ordered), vf direct from global.
  const u16* vbase = VT + (size_t)(b * 20 + h) * 64 * 128;
  f32x4 oacc[4];
#pragma unroll
  for (int dsm = 0; dsm < 4; dsm++) oacc[dsm] = (f32x4){0.f, 0.f, 0.f, 0.f};
#pragma unroll
  for (int ks = 0; ks < 4; ks++) {
    const short8 pf = *(const short8*)(P + (w * 4 + ks) * 512 + quad * 128 + l15 * 8);
#pragma unroll
    for (int dsm = 0; dsm < 4; dsm++) {
      const short8 vf = *(const short8*)(vbase + (size_t)(dsm * 16 + l15) * 128 + ks * 32 + quad * 8);
      oacc[dsm] = MFMA16(pf, vf, oacc[dsm], 0, 0, 0);
    }
  }
  u16* orow = O + ((size_t)b * 4096 + s0 + w * 16) * 1280 + h * 64;
#pragma unroll
  for (int dsm = 0; dsm < 4; dsm++)
#pragma unroll
    for (int r = 0; r < 4; r++)
      orow[(size_t)(quad * 4 + r) * 1280 + dsm * 16 + l15] = f2b(oacc[dsm][r]);
}

// ---------------------------------------------------------------------------
extern "C" void kernel_launch(void* const* d_in, const int* in_sizes, int n_in,
                              void* d_out, int out_size, void* d_ws, size_t ws_size,
                              hipStream_t stream) {
  const float* HS  = (const float*)d_in[0];   // [2][4096][1280] fp32
  const float* EHS = (const float*)d_in[1];   // [2][101][2048]  fp32
  const float* Wq  = (const float*)d_in[2];
  const float* Wo  = (const float*)d_in[11];
  const float* Bo  = (const float*)d_in[12];

  // workspace: ~28.7 MB. HSb aliases AO (HSb dead after Q-GEMM);
  // Qb (bf16 scratch) lives inside the fp32 d_out (dead before final write).
  u16* ws = (u16*)d_ws;
  u16* HSb  = ws;                      ws += (size_t)8192 * 1280;
  u16* AO   = HSb;
  u16* WqT  = ws;                      ws += (size_t)1280 * 1280;
  u16* WoT  = ws;                      ws += (size_t)1280 * 1280;
  u16* Kws  = ws;                      ws += (size_t)2 * 101 * 1280;
  u16* VTw  = ws;                      ws += (size_t)2 * 20 * 64 * 128;
  u16* Qb   = (u16*)d_out;
  (void)ws_size; (void)in_sizes; (void)n_in; (void)out_size;

  // zero VTw so pad keys [101,128) are 0 (attn reads them)
  hipMemsetAsync(VTw, 0, (size_t)2 * 20 * 64 * 128 * sizeof(u16), stream);

  // fp32 -> bf16 hidden states
  cvt_k<<<dim3(8192 * 1280 / 4 / 256), 256, 0, stream>>>(HS, HSb, 8192 * 1280);

  // Wq / Wo transpose (+convert)
  TransArgs ta;
  ta.src[0] = Wq; ta.dst[0] = WqT;
  ta.src[1] = Wo; ta.dst[1] = WoT;
  transpose_k<<<dim3(20, 20, 2), dim3(64, 8), 0, stream>>>(ta);

  // Q projection (bf16 out, into d_out scratch); 128x64 tiles
  gemm_bt<false><<<dim3(64, 20), 256, 0, stream>>>(HSb, WqT, Qb, nullptr,
                                                   8192, 1280, 1280, nullptr, nullptr);

  // KV projections (fp32 inputs read directly); BK=128 pipeline
  KVArgs ka;
  ka.ehs = EHS;
  for (int i = 0; i < 8; i++) ka.w[i] = (const float*)d_in[3 + i];
  ka.Kws = Kws; ka.VTws = VTw;
  kv_proj<<<dim3(32, 20), 256, 0, stream>>>(ka);

  // fused segmented attention (AO overwrites dead HSb)
  attn_k<<<dim3(64, 20, 2), 256, 0, stream>>>(Qb, Kws, VTw, AO);

  // out projection + bias + residual -> fp32 d_out (overwrites dead Qb)
  gemm_bt<true><<<dim3(64, 20), 256, 0, stream>>>(AO, WoT, nullptr, (float*)d_out,
                                                  8192, 1280, 1280, Bo, HS);
}